// Round 16
// baseline (257.930 us; speedup 1.0000x reference)
//
#include <hip/hip_runtime.h>
#include <hip/hip_bf16.h>
#include <math.h>

#define NN   50000
#define EE   800000
#define ETOT (EE + NN)
#define KDIM 256
#define HEADS 4
#define HIDD 64
#define DCAP 64   // fixed bucket capacity; deg ~ Poisson(16)+1, P(>64) ~ 1e-20

typedef float  f32x4  __attribute__((ext_vector_type(4)));
typedef short  bf16x8 __attribute__((ext_vector_type(8)));

__device__ __forceinline__ float b2f(unsigned short u) {
    union { float f; unsigned int i; } v; v.i = (unsigned int)u << 16; return v.f;
}
__device__ __forceinline__ unsigned short f2b(float f) {
    union { float f; unsigned int i; } v; v.f = f;
    return (unsigned short)((v.i + 0x7fffu + ((v.i >> 16) & 1u)) >> 16);
}
__device__ __forceinline__ float lrelu(float x) { return x >= 0.f ? x : 0.2f * x; }

// ---------------------------------------------------------------------------
// prep_k: weight casts only (deg zeroed by hipMemsetAsync).
// ---------------------------------------------------------------------------
#define CASTB 144

__global__ __launch_bounds__(256) void prep_k(
    const float* __restrict__ W1, const float* __restrict__ W2,
    const float* __restrict__ Wr, unsigned short* __restrict__ wout)
{
    int i = (blockIdx.x * 256 + threadIdx.x) * 4;
    const float* src;
    int off;
    if (i < 65536)        { src = W1; off = 0; }
    else if (i < 131072)  { src = W2; off = 65536; }
    else                  { src = Wr; off = 131072; }
    float4 v = *reinterpret_cast<const float4*>(src + (i - off));
    ushort4 o;
    o.x = f2b(v.x); o.y = f2b(v.y); o.z = f2b(v.z); o.w = f2b(v.w);
    *reinterpret_cast<ushort4*>(wout + i) = o;
}

// ---------------------------------------------------------------------------
// GEMM body (R15 structure, refactored to device fn with virtual block id).
// LDS-staged W, double-buffered K-slices of 32. Block: 4 waves x 16 rows.
// ---------------------------------------------------------------------------
template<bool AF32, int NCT, bool ALPHA, bool OUTF32>
__device__ __forceinline__ void gemm_body(
    unsigned short* __restrict__ WlRaw, int bid,
    const void* __restrict__ Ain, const unsigned short* __restrict__ W,
    void* __restrict__ Cout, int Mrows,
    const float* __restrict__ av_src, const float* __restrict__ av_dst,
    float* __restrict__ AS, float* __restrict__ AD,
    const float* __restrict__ bias0, const float* __restrict__ bias1)
{
    constexpr int ROWS = NCT * 16;
    constexpr int KS   = 32;
    constexpr int LDK  = 40;
    constexpr int NSL  = KDIM / KS;
    constexpr int NLD  = (ROWS * KS) / (256 * 8);
    // Wl[b][c][k] = WlRaw[(b*ROWS + c)*LDK + k]

    const int t    = threadIdx.x;
    const int wid  = t >> 6;
    const int lane = t & 63;
    const int cl   = lane & 15;
    const int kg   = lane >> 4;
    const int m0   = (bid * 4 + wid) * 16;

    int arow = m0 + cl; if (arow >= Mrows) arow = Mrows - 1;

    bf16x8 stg[NLD];
    auto LOADSTG = [&](int s) {
        #pragma unroll
        for (int i = 0; i < NLD; i++) {
            int f = i * 256 + t;
            int c = f >> 2, kc = f & 3;
            stg[i] = *reinterpret_cast<const bf16x8*>(
                W + (size_t)c * KDIM + s * KS + kc * 8);
        }
    };
    auto WRITESTG = [&](int b) {
        #pragma unroll
        for (int i = 0; i < NLD; i++) {
            int f = i * 256 + t;
            int c = f >> 2, kc = f & 3;
            *reinterpret_cast<bf16x8*>(&WlRaw[(size_t)(b * ROWS + c) * LDK + kc * 8]) = stg[i];
        }
    };
    auto LOADA = [&](int s) -> bf16x8 {
        if constexpr (AF32) {
            const float* ap = (const float*)Ain + (size_t)arow * KDIM + s * KS + kg * 8;
            float4 v0 = *reinterpret_cast<const float4*>(ap);
            float4 v1 = *reinterpret_cast<const float4*>(ap + 4);
            bf16x8 a;
            a[0] = (short)f2b(v0.x); a[1] = (short)f2b(v0.y);
            a[2] = (short)f2b(v0.z); a[3] = (short)f2b(v0.w);
            a[4] = (short)f2b(v1.x); a[5] = (short)f2b(v1.y);
            a[6] = (short)f2b(v1.z); a[7] = (short)f2b(v1.w);
            return a;
        } else {
            return *reinterpret_cast<const bf16x8*>(
                (const unsigned short*)Ain + (size_t)arow * KDIM + s * KS + kg * 8);
        }
    };

    f32x4 acc[NCT];
    #pragma unroll
    for (int ct = 0; ct < NCT; ct++) acc[ct] = (f32x4)(0.f);

    LOADSTG(0);
    WRITESTG(0);
    bf16x8 a_cur = LOADA(0);
    __syncthreads();

    int buf = 0;
    for (int s = 0; s < NSL; s++) {
        bf16x8 a_nxt;
        if (s + 1 < NSL) { LOADSTG(s + 1); a_nxt = LOADA(s + 1); }
        #pragma unroll
        for (int ct = 0; ct < NCT; ct++) {
            bf16x8 b = *reinterpret_cast<const bf16x8*>(
                &WlRaw[(size_t)(buf * ROWS + ct * 16 + cl) * LDK + kg * 8]);
            acc[ct] = __builtin_amdgcn_mfma_f32_16x16x32_bf16(a_cur, b, acc[ct], 0, 0, 0);
        }
        if (s + 1 < NSL) {
            WRITESTG(buf ^ 1);
            __syncthreads();
            buf ^= 1;
            a_cur = a_nxt;
        }
    }

    if constexpr (OUTF32) {
        float* C = (float*)Cout;
        #pragma unroll
        for (int ct = 0; ct < NCT; ct++) {
            #pragma unroll
            for (int r = 0; r < 4; r++) {
                int n = m0 + kg * 4 + r;
                int c = ct * 16 + cl;
                if (n < Mrows)
                    C[(size_t)n * (NCT * 16) + c] = acc[ct][r] + bias0[c] + bias1[c];
            }
        }
    } else {
        unsigned short* C = (unsigned short*)Cout;
        #pragma unroll
        for (int ct = 0; ct < NCT; ct++) {
            #pragma unroll
            for (int r = 0; r < 4; r++) {
                int n = m0 + kg * 4 + r;
                if (n < Mrows)
                    C[(size_t)n * (NCT * 16) + ct * 16 + cl] = f2b(acc[ct][r]);
            }
        }
    }

    if constexpr (ALPHA) {
        float asr[NCT], adr[NCT];
        #pragma unroll
        for (int ct = 0; ct < NCT; ct++) {
            int c = ct * 16 + cl;
            asr[ct] = av_src[c];
            adr[ct] = av_dst[c];
        }
        #pragma unroll
        for (int r = 0; r < 4; r++) {
            int n = m0 + kg * 4 + r;
            f32x4 s4 = (f32x4)(0.f), d4 = (f32x4)(0.f);
            #pragma unroll
            for (int h = 0; h < 4; h++) {
                #pragma unroll
                for (int q = 0; q < 4; q++) {
                    s4[h] += acc[h * 4 + q][r] * asr[h * 4 + q];
                    d4[h] += acc[h * 4 + q][r] * adr[h * 4 + q];
                }
            }
            #pragma unroll
            for (int msk = 1; msk <= 8; msk <<= 1) {
                #pragma unroll
                for (int h = 0; h < 4; h++) {
                    s4[h] += __shfl_xor(s4[h], msk, 64);
                    d4[h] += __shfl_xor(d4[h], msk, 64);
                }
            }
            if (cl == 0 && n < Mrows) {
                *reinterpret_cast<float4*>(AS + (size_t)n * 4) =
                    make_float4(s4[0], s4[1], s4[2], s4[3]);
                *reinterpret_cast<float4*>(AD + (size_t)n * 4) =
                    make_float4(d4[0], d4[1], d4[2], d4[3]);
            }
        }
    }
}

// ---------------------------------------------------------------------------
// mega1_k: block-range split — layer-1 GEMM ∥ root GEMM ∥ bucket-CSR fill.
// The fill part is latency-bound (random atomics + scattered 4B stores) and
// co-schedules with the BW/compute-bound GEMM waves on the same CUs.
// ---------------------------------------------------------------------------
#define MG ((NN + 63) / 64)              // 782 gemm blocks
#define EG ((ETOT + 255) / 256)          // 3321 fill blocks

__global__ __launch_bounds__(256) void mega1_k(
    const float* __restrict__ x, const unsigned short* __restrict__ w1b,
    unsigned short* __restrict__ Hb,
    const float* __restrict__ as1, const float* __restrict__ ad1,
    float* __restrict__ AS, float* __restrict__ AD,
    const float* __restrict__ root, const unsigned short* __restrict__ wrb,
    float* __restrict__ out, const float* __restrict__ br, const float* __restrict__ b2,
    const int* __restrict__ ei, int* __restrict__ deg, int* __restrict__ EDG)
{
    __shared__ unsigned short Wl[2 * 256 * 40];
    int b = blockIdx.x;
    if (b < MG) {
        gemm_body<true, 16, true, false>(Wl, b, x, w1b, Hb, NN,
                                         as1, ad1, AS, AD, nullptr, nullptr);
    } else if (b < 2 * MG) {
        gemm_body<true, 4, false, true>(Wl, b - MG, root, wrb, out, NN,
                                        nullptr, nullptr, nullptr, nullptr, br, b2);
    } else {
        int e = (b - 2 * MG) * 256 + threadIdx.x;
        if (e < ETOT) {
            int src, dst;
            if (e < EE) { src = ei[e]; dst = ei[EE + e]; }
            else        { src = dst = e - EE; }
            int pos = atomicAdd(deg + dst, 1) & (DCAP - 1);
            EDG[(size_t)dst * DCAP + pos] = src;
        }
    }
}

__global__ __launch_bounds__(256) void gemm2_k(
    const unsigned short* __restrict__ X2b, const unsigned short* __restrict__ w2b,
    unsigned short* __restrict__ Hb,
    const float* __restrict__ as2, const float* __restrict__ ad2,
    float* __restrict__ AS, float* __restrict__ AD)
{
    __shared__ unsigned short Wl[2 * 256 * 40];
    gemm_body<false, 16, true, false>(Wl, blockIdx.x, X2b, w2b, Hb, NN,
                                      as2, ad2, AS, AD, nullptr, nullptr);
}

// ---------------------------------------------------------------------------
// Single-pass gather-aggregate over fixed-capacity buckets (R15, unchanged).
// ---------------------------------------------------------------------------
template<int MODE>
__global__ __launch_bounds__(256) void gather_k(
    const int* __restrict__ deg, const int* __restrict__ EDG,
    const float* __restrict__ AS, const float* __restrict__ AD,
    const unsigned short* __restrict__ H, const float* __restrict__ bias,
    unsigned short* __restrict__ OUT, float* __restrict__ OUTF)
{
    __shared__ float wT[4][4][65];
    int wid  = threadIdx.x >> 6;
    int lane = threadIdx.x & 63;
    int n = blockIdx.x * 4 + wid;
    if (n >= NN) return;
    int head = lane >> 4;

    int cd = min(deg[n], DCAP);
    float4 ad4 = *reinterpret_cast<const float4*>(AD + (size_t)n * 4);

    int srcv = (lane < cd) ? EDG[(size_t)n * DCAP + lane] : 0;
    float4 w4 = make_float4(0.f, 0.f, 0.f, 0.f);
    if (lane < cd) {
        float4 s4 = *reinterpret_cast<const float4*>(AS + (size_t)srcv * 4);
        w4.x = __expf(lrelu(s4.x + ad4.x));
        w4.y = __expf(lrelu(s4.y + ad4.y));
        w4.z = __expf(lrelu(s4.z + ad4.z));
        w4.w = __expf(lrelu(s4.w + ad4.w));
    }
    wT[wid][0][lane] = w4.x;
    wT[wid][1][lane] = w4.y;
    wT[wid][2][lane] = w4.z;
    wT[wid][3][lane] = w4.w;

    float4 den4 = w4;
    #pragma unroll
    for (int msk = 1; msk <= 32; msk <<= 1) {
        den4.x += __shfl_xor(den4.x, msk, 64);
        den4.y += __shfl_xor(den4.y, msk, 64);
        den4.z += __shfl_xor(den4.z, msk, 64);
        den4.w += __shfl_xor(den4.w, msk, 64);
    }
    float den = head == 0 ? den4.x : head == 1 ? den4.y : head == 2 ? den4.z : den4.w;
    float inv = 1.f / den;   // self-loop guarantees den > 0

    float a0 = 0.f, a1 = 0.f, a2 = 0.f, a3 = 0.f;
    float c0 = 0.f, c1 = 0.f, c2 = 0.f, c3 = 0.f;
    const unsigned short* hp = H + lane * 4;

    int j = 0;
    for (; j + 4 <= cd; j += 4) {
        int   sA = __builtin_amdgcn_readlane(srcv, j);
        int   sB = __builtin_amdgcn_readlane(srcv, j + 1);
        int   sC = __builtin_amdgcn_readlane(srcv, j + 2);
        int   sD = __builtin_amdgcn_readlane(srcv, j + 3);
        float wA = wT[wid][head][j];
        float wB = wT[wid][head][j + 1];
        float wC = wT[wid][head][j + 2];
        float wD = wT[wid][head][j + 3];
        ushort4 hA = *reinterpret_cast<const ushort4*>(hp + (size_t)sA * 256);
        ushort4 hB = *reinterpret_cast<const ushort4*>(hp + (size_t)sB * 256);
        ushort4 hC = *reinterpret_cast<const ushort4*>(hp + (size_t)sC * 256);
        ushort4 hD = *reinterpret_cast<const ushort4*>(hp + (size_t)sD * 256);
        a0 += wA * b2f(hA.x); a1 += wA * b2f(hA.y);
        a2 += wA * b2f(hA.z); a3 += wA * b2f(hA.w);
        c0 += wB * b2f(hB.x); c1 += wB * b2f(hB.y);
        c2 += wB * b2f(hB.z); c3 += wB * b2f(hB.w);
        a0 += wC * b2f(hC.x); a1 += wC * b2f(hC.y);
        a2 += wC * b2f(hC.z); a3 += wC * b2f(hC.w);
        c0 += wD * b2f(hD.x); c1 += wD * b2f(hD.y);
        c2 += wD * b2f(hD.z); c3 += wD * b2f(hD.w);
    }
    for (; j < cd; j++) {
        int   sA = __builtin_amdgcn_readlane(srcv, j);
        float wA = wT[wid][head][j];
        ushort4 hA = *reinterpret_cast<const ushort4*>(hp + (size_t)sA * 256);
        a0 += wA * b2f(hA.x); a1 += wA * b2f(hA.y);
        a2 += wA * b2f(hA.z); a3 += wA * b2f(hA.w);
    }
    a0 += c0; a1 += c1; a2 += c2; a3 += c3;

    if (MODE == 1) {
        float4 bv = *reinterpret_cast<const float4*>(bias + lane * 4);
        ushort4 o;
        o.x = f2b(fmaxf(a0 * inv + bv.x, 0.f));
        o.y = f2b(fmaxf(a1 * inv + bv.y, 0.f));
        o.z = f2b(fmaxf(a2 * inv + bv.z, 0.f));
        o.w = f2b(fmaxf(a3 * inv + bv.w, 0.f));
        *reinterpret_cast<ushort4*>(OUT + (size_t)n * 256 + lane * 4) = o;
    } else {
        float v0 = a0 * inv, v1 = a1 * inv, v2 = a2 * inv, v3 = a3 * inv;
        #pragma unroll
        for (int msk = 16; msk <= 32; msk <<= 1) {
            v0 += __shfl_xor(v0, msk, 64);
            v1 += __shfl_xor(v1, msk, 64);
            v2 += __shfl_xor(v2, msk, 64);
            v3 += __shfl_xor(v3, msk, 64);
        }
        if (lane < 16) {
            float4* o = reinterpret_cast<float4*>(OUTF + (size_t)n * 64 + lane * 4);
            float4 cur = *o;
            cur.x += 0.25f * v0;
            cur.y += 0.25f * v1;
            cur.z += 0.25f * v2;
            cur.w += 0.25f * v3;
            *o = cur;
        }
    }
}

// ---------------------------------------------------------------------------
extern "C" void kernel_launch(void* const* d_in, const int* in_sizes, int n_in,
                              void* d_out, int out_size, void* d_ws, size_t ws_size,
                              hipStream_t stream) {
    const float* x    = (const float*)d_in[0];
    const float* root = (const float*)d_in[1];
    const int*   ei   = (const int*)  d_in[2];
    const float* W1   = (const float*)d_in[3];
    const float* as1  = (const float*)d_in[4];
    const float* ad1  = (const float*)d_in[5];
    const float* b1   = (const float*)d_in[6];
    const float* W2   = (const float*)d_in[7];
    const float* as2  = (const float*)d_in[8];
    const float* ad2  = (const float*)d_in[9];
    const float* b2   = (const float*)d_in[10];
    const float* Wr   = (const float*)d_in[11];
    const float* br   = (const float*)d_in[12];
    float* out = (float*)d_out;

    unsigned short* Hb  = (unsigned short*)d_ws;             // N*256
    unsigned short* X2b = Hb  + (size_t)NN * 256;            // N*256
    unsigned short* w1b = X2b + (size_t)NN * 256;            // 65536
    unsigned short* w2b = w1b + 65536;                       // 65536
    unsigned short* wrb = w2b + 65536;                       // 16384
    float* AS  = (float*)(wrb + 16384);                      // N*4
    float* AD  = AS + (size_t)NN * 4;                        // N*4
    int*   deg = (int*)(AD + (size_t)NN * 4);                // N
    int*   EDG = deg + NN;                                   // N*DCAP

    const int wgrid = (NN + 3) / 4;

    // deg = 0 (async memset) + weight casts
    hipMemsetAsync(deg, 0, NN * sizeof(int), stream);
    prep_k<<<CASTB, 256, 0, stream>>>(W1, W2, Wr, w1b);

    // layer-1 GEMM ∥ root GEMM ∥ bucket-CSR fill
    mega1_k<<<2 * MG + EG, 256, 0, stream>>>(x, w1b, Hb, as1, ad1, AS, AD,
                                             root, wrb, out, br, b2,
                                             ei, deg, EDG);
    gather_k<1><<<wgrid, 256, 0, stream>>>(deg, EDG, AS, AD, Hb, b1, X2b, nullptr);

    // layer 2
    gemm2_k<<<MG, 256, 0, stream>>>(X2b, w2b, Hb, as2, ad2, AS, AD);
    gather_k<2><<<wgrid, 256, 0, stream>>>(deg, EDG, AS, AD, Hb, nullptr, nullptr, out);
}

// Round 17
// 237.044 us; speedup vs baseline: 1.0881x; 1.0881x over previous
//
#include <hip/hip_runtime.h>
#include <hip/hip_bf16.h>
#include <math.h>

#define NN   50000
#define EE   800000
#define ETOT (EE + NN)
#define KDIM 256
#define HEADS 4
#define HIDD 64
#define DCAP 64   // fixed bucket capacity; deg ~ Poisson(16)+1, P(>64) ~ 1e-20

typedef float  f32x4  __attribute__((ext_vector_type(4)));
typedef short  bf16x8 __attribute__((ext_vector_type(8)));

__device__ __forceinline__ float b2f(unsigned short u) {
    union { float f; unsigned int i; } v; v.i = (unsigned int)u << 16; return v.f;
}
__device__ __forceinline__ unsigned short f2b(float f) {
    union { float f; unsigned int i; } v; v.f = f;
    return (unsigned short)((v.i + 0x7fffu + ((v.i >> 16) & 1u)) >> 16);
}
__device__ __forceinline__ float lrelu(float x) { return x >= 0.f ? x : 0.2f * x; }

// ---------------------------------------------------------------------------
// prep_k: weight casts only (deg zeroed by hipMemsetAsync).
// ---------------------------------------------------------------------------
#define CASTB 144

__global__ __launch_bounds__(256) void prep_k(
    const float* __restrict__ W1, const float* __restrict__ W2,
    const float* __restrict__ Wr, unsigned short* __restrict__ wout)
{
    int i = (blockIdx.x * 256 + threadIdx.x) * 4;
    const float* src;
    int off;
    if (i < 65536)        { src = W1; off = 0; }
    else if (i < 131072)  { src = W2; off = 65536; }
    else                  { src = Wr; off = 131072; }
    float4 v = *reinterpret_cast<const float4*>(src + (i - off));
    ushort4 o;
    o.x = f2b(v.x); o.y = f2b(v.y); o.z = f2b(v.z); o.w = f2b(v.w);
    *reinterpret_cast<ushort4*>(wout + i) = o;
}

// ---------------------------------------------------------------------------
// GEMM body (R15 structure). LDS-staged W, double-buffered K-slices of 32.
// 4 gemm waves x 16 rows = 64 rows per (virtual) block id.
// Executes EXACTLY 8 __syncthreads() (1 prologue + 7 in-loop) — the fill
// wave in mega1_k matches this count.
// ---------------------------------------------------------------------------
template<bool AF32, int NCT, bool ALPHA, bool OUTF32>
__device__ __forceinline__ void gemm_body(
    unsigned short (*__restrict__ Wl)[40], int bid,
    const void* __restrict__ Ain, const unsigned short* __restrict__ W,
    void* __restrict__ Cout, int Mrows,
    const float* __restrict__ av_src, const float* __restrict__ av_dst,
    float* __restrict__ AS, float* __restrict__ AD,
    const float* __restrict__ bias0, const float* __restrict__ bias1)
{
    constexpr int ROWS = NCT * 16;
    constexpr int KS   = 32;
    constexpr int NSL  = KDIM / KS;                 // 8
    constexpr int NLD  = (ROWS * KS) / (256 * 8);
    // buffer b rows live at Wl[b*ROWS + c]

    const int t    = threadIdx.x;                   // gemm waves: t in [0,256)
    const int wid  = t >> 6;
    const int lane = t & 63;
    const int cl   = lane & 15;
    const int kg   = lane >> 4;
    const int m0   = (bid * 4 + wid) * 16;

    int arow = m0 + cl; if (arow >= Mrows) arow = Mrows - 1;

    bf16x8 stg[NLD];
    auto LOADSTG = [&](int s) {
        #pragma unroll
        for (int i = 0; i < NLD; i++) {
            int f = i * 256 + t;
            int c = f >> 2, kc = f & 3;
            stg[i] = *reinterpret_cast<const bf16x8*>(
                W + (size_t)c * KDIM + s * KS + kc * 8);
        }
    };
    auto WRITESTG = [&](int b) {
        #pragma unroll
        for (int i = 0; i < NLD; i++) {
            int f = i * 256 + t;
            int c = f >> 2, kc = f & 3;
            *reinterpret_cast<bf16x8*>(&Wl[b * ROWS + c][kc * 8]) = stg[i];
        }
    };
    auto LOADA = [&](int s) -> bf16x8 {
        if constexpr (AF32) {
            const float* ap = (const float*)Ain + (size_t)arow * KDIM + s * KS + kg * 8;
            float4 v0 = *reinterpret_cast<const float4*>(ap);
            float4 v1 = *reinterpret_cast<const float4*>(ap + 4);
            bf16x8 a;
            a[0] = (short)f2b(v0.x); a[1] = (short)f2b(v0.y);
            a[2] = (short)f2b(v0.z); a[3] = (short)f2b(v0.w);
            a[4] = (short)f2b(v1.x); a[5] = (short)f2b(v1.y);
            a[6] = (short)f2b(v1.z); a[7] = (short)f2b(v1.w);
            return a;
        } else {
            return *reinterpret_cast<const bf16x8*>(
                (const unsigned short*)Ain + (size_t)arow * KDIM + s * KS + kg * 8);
        }
    };

    f32x4 acc[NCT];
    #pragma unroll
    for (int ct = 0; ct < NCT; ct++) acc[ct] = (f32x4)(0.f);

    LOADSTG(0);
    WRITESTG(0);
    bf16x8 a_cur = LOADA(0);
    __syncthreads();                                // barrier 1

    int buf = 0;
    for (int s = 0; s < NSL; s++) {
        bf16x8 a_nxt;
        if (s + 1 < NSL) { LOADSTG(s + 1); a_nxt = LOADA(s + 1); }
        #pragma unroll
        for (int ct = 0; ct < NCT; ct++) {
            bf16x8 b = *reinterpret_cast<const bf16x8*>(&Wl[buf * ROWS + ct * 16 + cl][kg * 8]);
            acc[ct] = __builtin_amdgcn_mfma_f32_16x16x32_bf16(a_cur, b, acc[ct], 0, 0, 0);
        }
        if (s + 1 < NSL) {
            WRITESTG(buf ^ 1);
            __syncthreads();                        // barriers 2..8
            buf ^= 1;
            a_cur = a_nxt;
        }
    }

    if constexpr (OUTF32) {
        float* C = (float*)Cout;
        #pragma unroll
        for (int ct = 0; ct < NCT; ct++) {
            #pragma unroll
            for (int r = 0; r < 4; r++) {
                int n = m0 + kg * 4 + r;
                int c = ct * 16 + cl;
                if (n < Mrows)
                    C[(size_t)n * (NCT * 16) + c] = acc[ct][r] + bias0[c] + bias1[c];
            }
        }
    } else {
        unsigned short* C = (unsigned short*)Cout;
        #pragma unroll
        for (int ct = 0; ct < NCT; ct++) {
            #pragma unroll
            for (int r = 0; r < 4; r++) {
                int n = m0 + kg * 4 + r;
                if (n < Mrows)
                    C[(size_t)n * (NCT * 16) + ct * 16 + cl] = f2b(acc[ct][r]);
            }
        }
    }

    if constexpr (ALPHA) {
        float asr[NCT], adr[NCT];
        #pragma unroll
        for (int ct = 0; ct < NCT; ct++) {
            int c = ct * 16 + cl;
            asr[ct] = av_src[c];
            adr[ct] = av_dst[c];
        }
        #pragma unroll
        for (int r = 0; r < 4; r++) {
            int n = m0 + kg * 4 + r;
            f32x4 s4 = (f32x4)(0.f), d4 = (f32x4)(0.f);
            #pragma unroll
            for (int h = 0; h < 4; h++) {
                #pragma unroll
                for (int q = 0; q < 4; q++) {
                    s4[h] += acc[h * 4 + q][r] * asr[h * 4 + q];
                    d4[h] += acc[h * 4 + q][r] * adr[h * 4 + q];
                }
            }
            #pragma unroll
            for (int msk = 1; msk <= 8; msk <<= 1) {
                #pragma unroll
                for (int h = 0; h < 4; h++) {
                    s4[h] += __shfl_xor(s4[h], msk, 64);
                    d4[h] += __shfl_xor(d4[h], msk, 64);
                }
            }
            if (cl == 0 && n < Mrows) {
                *reinterpret_cast<float4*>(AS + (size_t)n * 4) =
                    make_float4(s4[0], s4[1], s4[2], s4[3]);
                *reinterpret_cast<float4*>(AD + (size_t)n * 4) =
                    make_float4(d4[0], d4[1], d4[2], d4[3]);
            }
        }
    }
}

// ---------------------------------------------------------------------------
// mega1_k: 320-thread blocks. Waves 0-3: layer-1 GEMM (blocks < MG) or root
// GEMM (blocks >= MG). Wave 4: bucket-CSR fill slice (576 edges), interleaved
// with 8 __syncthreads() to match gemm_body's barrier count — each fill round
// hides under one gemm K-slice. Fill costs no extra LDS/blocks (R16 lesson).
// ---------------------------------------------------------------------------
#define MG   ((NN + 63) / 64)            // 782 gemm block-ids per matmul
#define FCH  576                          // edges per block; 2*MG*576 >= ETOT

__global__ __launch_bounds__(320) void mega1_k(
    const float* __restrict__ x, const unsigned short* __restrict__ w1b,
    unsigned short* __restrict__ Hb,
    const float* __restrict__ as1, const float* __restrict__ ad1,
    float* __restrict__ AS, float* __restrict__ AD,
    const float* __restrict__ root, const unsigned short* __restrict__ wrb,
    float* __restrict__ out, const float* __restrict__ br, const float* __restrict__ b2,
    const int* __restrict__ ei, int* __restrict__ deg, int* __restrict__ EDG)
{
    __shared__ unsigned short Wl[2 * 256][40];
    const int b = blockIdx.x;
    const int wid = threadIdx.x >> 6;

    if (wid < 4) {
        if (b < MG)
            gemm_body<true, 16, true, false>(Wl, b, x, w1b, Hb, NN,
                                             as1, ad1, AS, AD, nullptr, nullptr);
        else
            gemm_body<true, 4, false, true>(Wl, b - MG, root, wrb, out, NN,
                                            nullptr, nullptr, nullptr, nullptr, br, b2);
    } else {
        const int lane = threadIdx.x & 63;
        const int base = b * FCH;
        auto doEdge = [&](int e) {
            if (e < ETOT) {
                int src, dst;
                if (e < EE) { src = ei[e]; dst = ei[EE + e]; }
                else        { src = dst = e - EE; }
                int pos = atomicAdd(deg + dst, 1) & (DCAP - 1);
                EDG[(size_t)dst * DCAP + pos] = src;
            }
        };
        #pragma unroll
        for (int s = 0; s < 8; s++) {
            doEdge(base + s * 72 + lane);
            if (lane < 8) doEdge(base + s * 72 + 64 + lane);
            __syncthreads();                        // match gemm barriers 1..8
        }
    }
}

__global__ __launch_bounds__(256) void gemm2_k(
    const unsigned short* __restrict__ X2b, const unsigned short* __restrict__ w2b,
    unsigned short* __restrict__ Hb,
    const float* __restrict__ as2, const float* __restrict__ ad2,
    float* __restrict__ AS, float* __restrict__ AD)
{
    __shared__ unsigned short Wl[2 * 256][40];
    gemm_body<false, 16, true, false>(Wl, blockIdx.x, X2b, w2b, Hb, NN,
                                      as2, ad2, AS, AD, nullptr, nullptr);
}

// ---------------------------------------------------------------------------
// Single-pass gather-aggregate over fixed-capacity buckets (R15, unchanged).
// ---------------------------------------------------------------------------
template<int MODE>
__global__ __launch_bounds__(256) void gather_k(
    const int* __restrict__ deg, const int* __restrict__ EDG,
    const float* __restrict__ AS, const float* __restrict__ AD,
    const unsigned short* __restrict__ H, const float* __restrict__ bias,
    unsigned short* __restrict__ OUT, float* __restrict__ OUTF)
{
    __shared__ float wT[4][4][65];
    int wid  = threadIdx.x >> 6;
    int lane = threadIdx.x & 63;
    int n = blockIdx.x * 4 + wid;
    if (n >= NN) return;
    int head = lane >> 4;

    int cd = min(deg[n], DCAP);
    float4 ad4 = *reinterpret_cast<const float4*>(AD + (size_t)n * 4);

    int srcv = (lane < cd) ? EDG[(size_t)n * DCAP + lane] : 0;
    float4 w4 = make_float4(0.f, 0.f, 0.f, 0.f);
    if (lane < cd) {
        float4 s4 = *reinterpret_cast<const float4*>(AS + (size_t)srcv * 4);
        w4.x = __expf(lrelu(s4.x + ad4.x));
        w4.y = __expf(lrelu(s4.y + ad4.y));
        w4.z = __expf(lrelu(s4.z + ad4.z));
        w4.w = __expf(lrelu(s4.w + ad4.w));
    }
    wT[wid][0][lane] = w4.x;
    wT[wid][1][lane] = w4.y;
    wT[wid][2][lane] = w4.z;
    wT[wid][3][lane] = w4.w;

    float4 den4 = w4;
    #pragma unroll
    for (int msk = 1; msk <= 32; msk <<= 1) {
        den4.x += __shfl_xor(den4.x, msk, 64);
        den4.y += __shfl_xor(den4.y, msk, 64);
        den4.z += __shfl_xor(den4.z, msk, 64);
        den4.w += __shfl_xor(den4.w, msk, 64);
    }
    float den = head == 0 ? den4.x : head == 1 ? den4.y : head == 2 ? den4.z : den4.w;
    float inv = 1.f / den;   // self-loop guarantees den > 0

    float a0 = 0.f, a1 = 0.f, a2 = 0.f, a3 = 0.f;
    float c0 = 0.f, c1 = 0.f, c2 = 0.f, c3 = 0.f;
    const unsigned short* hp = H + lane * 4;

    int j = 0;
    for (; j + 4 <= cd; j += 4) {
        int   sA = __builtin_amdgcn_readlane(srcv, j);
        int   sB = __builtin_amdgcn_readlane(srcv, j + 1);
        int   sC = __builtin_amdgcn_readlane(srcv, j + 2);
        int   sD = __builtin_amdgcn_readlane(srcv, j + 3);
        float wA = wT[wid][head][j];
        float wB = wT[wid][head][j + 1];
        float wC = wT[wid][head][j + 2];
        float wD = wT[wid][head][j + 3];
        ushort4 hA = *reinterpret_cast<const ushort4*>(hp + (size_t)sA * 256);
        ushort4 hB = *reinterpret_cast<const ushort4*>(hp + (size_t)sB * 256);
        ushort4 hC = *reinterpret_cast<const ushort4*>(hp + (size_t)sC * 256);
        ushort4 hD = *reinterpret_cast<const ushort4*>(hp + (size_t)sD * 256);
        a0 += wA * b2f(hA.x); a1 += wA * b2f(hA.y);
        a2 += wA * b2f(hA.z); a3 += wA * b2f(hA.w);
        c0 += wB * b2f(hB.x); c1 += wB * b2f(hB.y);
        c2 += wB * b2f(hB.z); c3 += wB * b2f(hB.w);
        a0 += wC * b2f(hC.x); a1 += wC * b2f(hC.y);
        a2 += wC * b2f(hC.z); a3 += wC * b2f(hC.w);
        c0 += wD * b2f(hD.x); c1 += wD * b2f(hD.y);
        c2 += wD * b2f(hD.z); c3 += wD * b2f(hD.w);
    }
    for (; j < cd; j++) {
        int   sA = __builtin_amdgcn_readlane(srcv, j);
        float wA = wT[wid][head][j];
        ushort4 hA = *reinterpret_cast<const ushort4*>(hp + (size_t)sA * 256);
        a0 += wA * b2f(hA.x); a1 += wA * b2f(hA.y);
        a2 += wA * b2f(hA.z); a3 += wA * b2f(hA.w);
    }
    a0 += c0; a1 += c1; a2 += c2; a3 += c3;

    if (MODE == 1) {
        float4 bv = *reinterpret_cast<const float4*>(bias + lane * 4);
        ushort4 o;
        o.x = f2b(fmaxf(a0 * inv + bv.x, 0.f));
        o.y = f2b(fmaxf(a1 * inv + bv.y, 0.f));
        o.z = f2b(fmaxf(a2 * inv + bv.z, 0.f));
        o.w = f2b(fmaxf(a3 * inv + bv.w, 0.f));
        *reinterpret_cast<ushort4*>(OUT + (size_t)n * 256 + lane * 4) = o;
    } else {
        float v0 = a0 * inv, v1 = a1 * inv, v2 = a2 * inv, v3 = a3 * inv;
        #pragma unroll
        for (int msk = 16; msk <= 32; msk <<= 1) {
            v0 += __shfl_xor(v0, msk, 64);
            v1 += __shfl_xor(v1, msk, 64);
            v2 += __shfl_xor(v2, msk, 64);
            v3 += __shfl_xor(v3, msk, 64);
        }
        if (lane < 16) {
            float4* o = reinterpret_cast<float4*>(OUTF + (size_t)n * 64 + lane * 4);
            float4 cur = *o;
            cur.x += 0.25f * v0;
            cur.y += 0.25f * v1;
            cur.z += 0.25f * v2;
            cur.w += 0.25f * v3;
            *o = cur;
        }
    }
}

// ---------------------------------------------------------------------------
extern "C" void kernel_launch(void* const* d_in, const int* in_sizes, int n_in,
                              void* d_out, int out_size, void* d_ws, size_t ws_size,
                              hipStream_t stream) {
    const float* x    = (const float*)d_in[0];
    const float* root = (const float*)d_in[1];
    const int*   ei   = (const int*)  d_in[2];
    const float* W1   = (const float*)d_in[3];
    const float* as1  = (const float*)d_in[4];
    const float* ad1  = (const float*)d_in[5];
    const float* b1   = (const float*)d_in[6];
    const float* W2   = (const float*)d_in[7];
    const float* as2  = (const float*)d_in[8];
    const float* ad2  = (const float*)d_in[9];
    const float* b2   = (const float*)d_in[10];
    const float* Wr   = (const float*)d_in[11];
    const float* br   = (const float*)d_in[12];
    float* out = (float*)d_out;

    unsigned short* Hb  = (unsigned short*)d_ws;             // N*256
    unsigned short* X2b = Hb  + (size_t)NN * 256;            // N*256
    unsigned short* w1b = X2b + (size_t)NN * 256;            // 65536
    unsigned short* w2b = w1b + 65536;                       // 65536
    unsigned short* wrb = w2b + 65536;                       // 16384
    float* AS  = (float*)(wrb + 16384);                      // N*4
    float* AD  = AS + (size_t)NN * 4;                        // N*4
    int*   deg = (int*)(AD + (size_t)NN * 4);                // N
    int*   EDG = deg + NN;                                   // N*DCAP

    const int wgrid = (NN + 3) / 4;

    // deg = 0 (async memset) + weight casts
    hipMemsetAsync(deg, 0, NN * sizeof(int), stream);
    prep_k<<<CASTB, 256, 0, stream>>>(W1, W2, Wr, w1b);

    // layer-1 GEMM ∥ root GEMM (waves 0-3) ∥ bucket-CSR fill (wave 4)
    mega1_k<<<2 * MG, 320, 0, stream>>>(x, w1b, Hb, as1, ad1, AS, AD,
                                        root, wrb, out, br, b2,
                                        ei, deg, EDG);
    gather_k<1><<<wgrid, 256, 0, stream>>>(deg, EDG, AS, AD, Hb, b1, X2b, nullptr);

    // layer 2
    gemm2_k<<<MG, 256, 0, stream>>>(X2b, w2b, Hb, as2, ad2, AS, AD);
    gather_k<2><<<wgrid, 256, 0, stream>>>(deg, EDG, AS, AD, Hb, nullptr, nullptr, out);
}